// Round 9
// baseline (451.196 us; speedup 1.0000x reference)
//
#include <hip/hip_runtime.h>

#define EPS 1e-5f

typedef __attribute__((ext_vector_type(8))) short bf16x8;
typedef __attribute__((ext_vector_type(4))) float f32x4;

#define GLOBAL_LOAD_LDS16(gp, lp) \
    __builtin_amdgcn_global_load_lds((const __attribute__((address_space(1))) unsigned int*)(gp), \
                                     (__attribute__((address_space(3))) unsigned int*)(lp), 16, 0, 0)

// Split f32 -> bf16 hi (truncated) + bf16 lo (residual, truncated).
static __device__ __forceinline__ void split8(float4 f0, float4 f1, bf16x8& hi, bf16x8& lo) {
    float f[8] = {f0.x, f0.y, f0.z, f0.w, f1.x, f1.y, f1.z, f1.w};
    bf16x8 h, l;
#pragma unroll
    for (int i = 0; i < 8; ++i) {
        unsigned u = __float_as_uint(f[i]);
        h[i] = (short)(u >> 16);
        float r = f[i] - __uint_as_float(u & 0xffff0000u);
        l[i] = (short)(__float_as_uint(r) >> 16);
    }
    hi = h; lo = l;
}

// ================= CSR build =================
__global__ __launch_bounds__(256) void hist_kernel(
    const int* __restrict__ ei, int* __restrict__ deg, int E)
{
    int e = blockIdx.x * 256 + threadIdx.x;
    if (e >= E) return;
    atomicAdd(&deg[ei[E + e]], 1);
}

__global__ __launch_bounds__(256) void blocksum_kernel(
    const int* __restrict__ deg, int* __restrict__ bsum, int N)
{
    int i = blockIdx.x * 256 + threadIdx.x;
    int v = (i < N) ? deg[i] : 0;
#pragma unroll
    for (int o = 1; o < 64; o <<= 1) v += __shfl_xor(v, o);
    __shared__ int s[4];
    if ((threadIdx.x & 63) == 0) s[threadIdx.x >> 6] = v;
    __syncthreads();
    if (threadIdx.x == 0) bsum[blockIdx.x] = s[0] + s[1] + s[2] + s[3];
}

__global__ __launch_bounds__(512) void scanb_kernel(int* bsum, int NB)
{
    __shared__ int sh[512];
    int t = threadIdx.x;
    int v = (t < NB) ? bsum[t] : 0;
    sh[t] = v;
    __syncthreads();
    for (int o = 1; o < 512; o <<= 1) {
        int add = (t >= o) ? sh[t - o] : 0;
        __syncthreads();
        sh[t] += add;
        __syncthreads();
    }
    if (t < NB) bsum[t] = (t == 0) ? 0 : sh[t - 1];
}

__global__ __launch_bounds__(256) void scanfinal_kernel(
    const int* __restrict__ deg, const int* __restrict__ bsum,
    int* __restrict__ rowptr, int* __restrict__ cursor, int N)
{
    int b = blockIdx.x, t = threadIdx.x;
    int i = b * 256 + t;
    int v = (i < N) ? deg[i] : 0;
    __shared__ int sh[256];
    sh[t] = v;
    __syncthreads();
    for (int o = 1; o < 256; o <<= 1) {
        int add = (t >= o) ? sh[t - o] : 0;
        __syncthreads();
        sh[t] += add;
        __syncthreads();
    }
    int excl = sh[t] - v;
    if (i < N) {
        int rp = bsum[b] + excl;
        rowptr[i] = rp;
        cursor[i] = rp;
        if (i == N - 1) rowptr[N] = rp + v;
    }
}

__global__ __launch_bounds__(256) void fill_kernel(
    const int* __restrict__ ei, int* __restrict__ cursor, int* __restrict__ col, int E)
{
    int e = blockIdx.x * 256 + threadIdx.x;
    if (e >= E) return;
    int d = ei[E + e];
    int pos = atomicAdd(&cursor[d], 1);
    col[pos] = ei[e];
}

// ================= CSR gather =================
__global__ __launch_bounds__(256) void gather_kernel(
    const float* __restrict__ feat, float* __restrict__ agg,
    const int* __restrict__ rowptr, const int* __restrict__ col, int N)
{
    int gid = blockIdx.x * 256 + threadIdx.x;
    int n = gid >> 5;
    if (n >= N) return;
    int l = gid & 31;
    int beg = rowptr[n], end = rowptr[n + 1];
    float a0x = 0.f, a0y = 0.f, a0z = 0.f, a0w = 0.f;
    float a1x = 0.f, a1y = 0.f, a1z = 0.f, a1w = 0.f;
    int e = beg;
    for (; e + 2 <= end; e += 2) {
        int s0 = col[e], s1 = col[e + 1];
        float4 v0 = *(const float4*)(feat + (size_t)s0 * 128 + l * 4);
        float4 v1 = *(const float4*)(feat + (size_t)s1 * 128 + l * 4);
        a0x += v0.x; a0y += v0.y; a0z += v0.z; a0w += v0.w;
        a1x += v1.x; a1y += v1.y; a1z += v1.z; a1w += v1.w;
    }
    if (e < end) {
        int s0 = col[e];
        float4 v0 = *(const float4*)(feat + (size_t)s0 * 128 + l * 4);
        a0x += v0.x; a0y += v0.y; a0z += v0.z; a0w += v0.w;
    }
    *(float4*)(agg + (size_t)n * 128 + l * 4) =
        make_float4(a0x + a1x, a0y + a1y, a0z + a1z, a0w + a1w);
}

// ================= weight prepack: f32 [128][128] -> packed per-matrix [hi|lo] planes =================
// Matrix m occupies wPk[m*32768 .. +32768): first 16384 = hi plane, next 16384 = lo plane.
// Plane layout: [kb][cf][lane][j8]: element W[kb*32 + (lane>>4)*8 + j][cf*16 + (lane&15)].
__global__ __launch_bounds__(256) void prepack_kernel(
    const float* __restrict__ W0, const float* __restrict__ W1,
    const float* __restrict__ W2, const float* __restrict__ W3,
    const float* __restrict__ W4, const float* __restrict__ W5,
    ushort* __restrict__ wPk)
{
    int m = blockIdx.y;
    const float* W = (m == 0) ? W0 : (m == 1) ? W1 : (m == 2) ? W2
                   : (m == 3) ? W3 : (m == 4) ? W4 : W5;
    int base = m * 32768;
#pragma unroll
    for (int t = 0; t < 8; ++t) {
        int idx = blockIdx.x * 2048 + t * 256 + threadIdx.x;
        int j = idx & 7, l = (idx >> 3) & 63, cf = (idx >> 9) & 7, kb = idx >> 12;
        int k = kb * 32 + (l >> 4) * 8 + j;
        int n = cf * 16 + (l & 15);
        float v = W[k * 128 + n];
        unsigned u = __float_as_uint(v);
        wPk[base + idx] = (ushort)(u >> 16);
        float r = v - __uint_as_float(u & 0xffff0000u);
        wPk[base + 16384 + idx] = (ushort)(__float_as_uint(r) >> 16);
    }
}

// ================= MFMA linear: Y = Xa@Wa (+ Xb@Wb) + bias, split-bf16 3-term =================
// 64-row blocks (4 waves x 16 rows, acc = 32 VGPR) for occupancy: LDS 33KB -> 4 blocks/CU,
// launch_bounds(256,4) -> 16 waves/CU ceiling (round-8 was stuck at 8 waves/CU; the
// serialized L2-latency B-fragment loads need TLP to overlap).
// A staged global->LDS (gload_lds w16, coalesced src, XOR-swizzle both sides).

template<int DUAL>
static __device__ __forceinline__ void stageA(
    const float* __restrict__ Xa, const float* __restrict__ Xb,
    float* sbuf, int rbase0, int wid, int lane, int nrows, int kb)
{
    const int rl8 = lane >> 3;                 // 0..7
    const int c   = lane & 7;                  // 16B unit
#pragma unroll
    for (int u = 0; u < 2; ++u) {
        int row_local = wid * 16 + u * 8 + rl8;
        int gr = rbase0 + row_local;
        if (gr > nrows - 1) gr = nrows - 1;
        int xu = c ^ (row_local & 7);
        const float* ga = Xa + (size_t)gr * 128 + kb * 32 + xu * 4;
        float* la = sbuf + (size_t)(wid * 16 + u * 8) * 32;
        GLOBAL_LOAD_LDS16(ga, la);
        if (DUAL) {
            const float* gb = Xb + (size_t)gr * 128 + kb * 32 + xu * 4;
            float* lb = sbuf + 2048 + (size_t)(wid * 16 + u * 8) * 32;
            GLOBAL_LOAD_LDS16(gb, lb);
        }
    }
}

template<int DUAL>
static __device__ __forceinline__ void computeK(
    const float* sbuf, const ushort* __restrict__ WaPk, const ushort* __restrict__ WbPk,
    int lane, int wid, int kb, f32x4 (&acc)[8])
{
    const int q = lane >> 4, s = lane & 15;
    const int row = wid * 16 + s;
    const int sw = row & 7;
    bf16x8 ah, al, gh, gl;
    {
        float4 f0 = *(const float4*)(sbuf + row * 32 + ((2 * q + 0) ^ sw) * 4);
        float4 f1 = *(const float4*)(sbuf + row * 32 + ((2 * q + 1) ^ sw) * 4);
        split8(f0, f1, ah, al);
        if (DUAL) {
            float4 g0 = *(const float4*)(sbuf + 2048 + row * 32 + ((2 * q + 0) ^ sw) * 4);
            float4 g1 = *(const float4*)(sbuf + 2048 + row * 32 + ((2 * q + 1) ^ sw) * 4);
            split8(g0, g1, gh, gl);
        }
    }
#pragma unroll
    for (int cf = 0; cf < 8; ++cf) {
        int boff = ((kb * 8 + cf) * 64 + lane) * 8;
        bf16x8 bh = *(const bf16x8*)(WaPk + boff);
        bf16x8 bl = *(const bf16x8*)(WaPk + 16384 + boff);
        acc[cf] = __builtin_amdgcn_mfma_f32_16x16x32_bf16(ah, bh, acc[cf], 0, 0, 0);
        acc[cf] = __builtin_amdgcn_mfma_f32_16x16x32_bf16(al, bh, acc[cf], 0, 0, 0);
        acc[cf] = __builtin_amdgcn_mfma_f32_16x16x32_bf16(ah, bl, acc[cf], 0, 0, 0);
        if (DUAL) {
            bf16x8 ch = *(const bf16x8*)(WbPk + boff);
            bf16x8 cl = *(const bf16x8*)(WbPk + 16384 + boff);
            acc[cf] = __builtin_amdgcn_mfma_f32_16x16x32_bf16(gh, ch, acc[cf], 0, 0, 0);
            acc[cf] = __builtin_amdgcn_mfma_f32_16x16x32_bf16(gl, ch, acc[cf], 0, 0, 0);
            acc[cf] = __builtin_amdgcn_mfma_f32_16x16x32_bf16(gh, cl, acc[cf], 0, 0, 0);
        }
    }
}

template<int DUAL, int RELU, int STATS>
__global__ __launch_bounds__(256, 4) void mfma_lin_kernel(
    const float* __restrict__ Xa, const float* __restrict__ Xb,
    const ushort* __restrict__ WaPk, const ushort* __restrict__ WbPk,
    const float* __restrict__ bias, float* __restrict__ Y,
    float* __restrict__ st, int nrows)
{
    __shared__ float sA[2][(DUAL ? 2 : 1) * 2048];   // [buf][input][64 rows x 32 f32]
    __shared__ float sSum[128], sSq[128];
    const int tid  = threadIdx.x;
    const int lane = tid & 63;
    const int wid  = tid >> 6;
    const int q = lane >> 4, s = lane & 15;
    const int rbase0 = blockIdx.x * 64;

    if (STATS) {
        if (tid < 128) sSum[tid] = 0.f;
        else           sSq[tid - 128] = 0.f;
    }

    f32x4 acc[8];
#pragma unroll
    for (int cf = 0; cf < 8; ++cf)
        acc[cf] = (f32x4){0.f, 0.f, 0.f, 0.f};

    stageA<DUAL>(Xa, Xb, sA[0], rbase0, wid, lane, nrows, 0);
    __syncthreads();
    stageA<DUAL>(Xa, Xb, sA[1], rbase0, wid, lane, nrows, 1);
    computeK<DUAL>(sA[0], WaPk, WbPk, lane, wid, 0, acc);
    __syncthreads();
    stageA<DUAL>(Xa, Xb, sA[0], rbase0, wid, lane, nrows, 2);
    computeK<DUAL>(sA[1], WaPk, WbPk, lane, wid, 1, acc);
    __syncthreads();
    stageA<DUAL>(Xa, Xb, sA[1], rbase0, wid, lane, nrows, 3);
    computeK<DUAL>(sA[0], WaPk, WbPk, lane, wid, 2, acc);
    __syncthreads();
    computeK<DUAL>(sA[1], WaPk, WbPk, lane, wid, 3, acc);

    // epilogue: bias (+relu) + store + fused column stats
#pragma unroll
    for (int cf = 0; cf < 8; ++cf) {
        int colc = cf * 16 + s;
        float bv = bias[colc];
        float cs = 0.f, cq = 0.f;
        int r0 = rbase0 + wid * 16 + q * 4;
#pragma unroll
        for (int i = 0; i < 4; ++i) {
            int r = r0 + i;
            float y = acc[cf][i] + bv;
            if (RELU) y = fmaxf(y, 0.f);
            if (r < nrows) {
                Y[(size_t)r * 128 + colc] = y;
                if (STATS) { cs += y; cq += y * y; }
            }
        }
        if (STATS) {
            cs += __shfl_xor(cs, 16); cs += __shfl_xor(cs, 32);
            cq += __shfl_xor(cq, 16); cq += __shfl_xor(cq, 32);
            if (q == 0) { atomicAdd(&sSum[colc], cs); atomicAdd(&sSq[colc], cq); }
        }
    }
    if (STATS) {
        __syncthreads();
        if (tid < 128)      atomicAdd(&st[tid], sSum[tid]);
        else if (tid < 256) atomicAdd(&st[tid], sSq[tid - 128]);
    }
}

// ================= BN finalize =================
__global__ void finalize_kernel(float* st, float inv_n) {
    int c = threadIdx.x;
    float mu = st[c] * inv_n;
    float var = st[128 + c] * inv_n - mu * mu;
    st[256 + c] = mu;
    st[384 + c] = rsqrtf(var + EPS);
}

// ================= BN normalize + ReLU (in place) =================
__global__ __launch_bounds__(256) void bnrelu_kernel(
    float* __restrict__ H, const float* __restrict__ st,
    const float* __restrict__ gamma, const float* __restrict__ beta, int n4)
{
    for (int i = blockIdx.x * 256 + threadIdx.x; i < n4; i += gridDim.x * 256) {
        int c4 = i & 31;
        float4 h = ((float4*)H)[i];
        float4 mu = *(const float4*)(st + 256 + c4 * 4);
        float4 rs = *(const float4*)(st + 384 + c4 * 4);
        float4 g  = *(const float4*)(gamma + c4 * 4);
        float4 b  = *(const float4*)(beta + c4 * 4);
        h.x = fmaxf((h.x - mu.x) * rs.x * g.x + b.x, 0.f);
        h.y = fmaxf((h.y - mu.y) * rs.y * g.y + b.y, 0.f);
        h.z = fmaxf((h.z - mu.z) * rs.z * g.z + b.z, 0.f);
        h.w = fmaxf((h.w - mu.w) * rs.w * g.w + b.w, 0.f);
        ((float4*)H)[i] = h;
    }
}

// ================= final projection to DOUT=2 =================
__global__ __launch_bounds__(256) void linout_kernel(
    const float* __restrict__ X, const float* __restrict__ W, const float* __restrict__ b,
    float* __restrict__ out, int nrows)
{
    int r = blockIdx.x * 256 + threadIdx.x;
    if (r >= nrows) return;
    float a0 = 0.f, a1 = 0.f;
    const float* xr = X + (size_t)r * 128;
#pragma unroll 8
    for (int k = 0; k < 128; k += 4) {
        float4 x = *(const float4*)(xr + k);
        a0 += x.x * W[(k + 0) * 2]     + x.y * W[(k + 1) * 2]
            + x.z * W[(k + 2) * 2]     + x.w * W[(k + 3) * 2];
        a1 += x.x * W[(k + 0) * 2 + 1] + x.y * W[(k + 1) * 2 + 1]
            + x.z * W[(k + 2) * 2 + 1] + x.w * W[(k + 3) * 2 + 1];
    }
    float2 o = make_float2(a0 + b[0], a1 + b[1]);
    *(float2*)(out + (size_t)r * 2) = o;
}

extern "C" void kernel_launch(void* const* d_in, const int* in_sizes, int n_in,
                              void* d_out, int out_size, void* d_ws, size_t ws_size,
                              hipStream_t stream) {
    const float* x   = (const float*)d_in[0];
    const int*   ei  = (const int*)d_in[1];
    const float* Wl0 = (const float*)d_in[2];
    const float* bl0 = (const float*)d_in[3];
    const float* Wr0 = (const float*)d_in[4];
    const float* Wl1 = (const float*)d_in[5];
    const float* bl1 = (const float*)d_in[6];
    const float* Wr1 = (const float*)d_in[7];
    const float* g0  = (const float*)d_in[8];
    const float* be0 = (const float*)d_in[9];
    const float* g1  = (const float*)d_in[10];
    const float* be1 = (const float*)d_in[11];
    const float* W1  = (const float*)d_in[12];
    const float* b1  = (const float*)d_in[13];
    const float* W2  = (const float*)d_in[14];
    const float* b2  = (const float*)d_in[15];
    const float* W3  = (const float*)d_in[16];
    const float* b3  = (const float*)d_in[17];
    float* out = (float*)d_out;

    const int N = in_sizes[0] / 128;
    const int E = in_sizes[1] / 2;

    // workspace layout
    float* A  = (float*)d_ws;                    // [N,128]
    float* B  = A + (size_t)N * 128;             // [N,128]
    float* st = B + (size_t)N * 128;             // 512 floats
    ushort* wPk = (ushort*)(st + 512);           // 6 * 32768 (per-matrix [hi|lo])
    int* deg    = (int*)(wPk + 6 * 32768);       // N
    int* rowptr = deg + N;                       // N+1
    int* cursor = rowptr + N + 1;                // N
    int* col    = cursor + N;                    // E
    int* bsum   = col + E;                       // <=512

    const int linGrid    = (N + 63) / 64;
    const int edgeGrid   = (E + 255) / 256;
    const int nodeGrid   = (N + 255) / 256;
    const int gatherGrid = ((size_t)N * 32 + 255) / 256;
    const float inv_n = 1.0f / (float)N;

    // matrix slots: 0=Wl0 1=Wr0 2=Wl1 3=Wr1 4=W1 5=W2
    prepack_kernel<<<dim3(8, 6), 256, 0, stream>>>(Wl0, Wr0, Wl1, Wr1, W1, W2, wPk);

    // ----- CSR build -----
    hipMemsetAsync(deg, 0, (size_t)N * sizeof(int), stream);
    hist_kernel<<<edgeGrid, 256, 0, stream>>>(ei, deg, E);
    blocksum_kernel<<<nodeGrid, 256, 0, stream>>>(deg, bsum, N);
    scanb_kernel<<<1, 512, 0, stream>>>(bsum, nodeGrid);
    scanfinal_kernel<<<nodeGrid, 256, 0, stream>>>(deg, bsum, rowptr, cursor, N);
    fill_kernel<<<edgeGrid, 256, 0, stream>>>(ei, cursor, col, E);

    // ----- layer 0: h0 = agg(x)@Wl0 + x@Wr0 + bl0, fused stats -----
    gather_kernel<<<gatherGrid, 256, 0, stream>>>(x, A, rowptr, col, N);
    hipMemsetAsync(st, 0, 256 * sizeof(float), stream);
    mfma_lin_kernel<1, 0, 1><<<linGrid, 256, 0, stream>>>(
        A, x, wPk, wPk + 32768, bl0, A, st, N);
    finalize_kernel<<<1, 128, 0, stream>>>(st, inv_n);
    bnrelu_kernel<<<2048, 256, 0, stream>>>(A, st, g0, be0, N * 32);

    // ----- layer 1 -----
    gather_kernel<<<gatherGrid, 256, 0, stream>>>(A, B, rowptr, col, N);
    hipMemsetAsync(st, 0, 256 * sizeof(float), stream);
    mfma_lin_kernel<1, 0, 1><<<linGrid, 256, 0, stream>>>(
        B, A, wPk + 2 * 32768, wPk + 3 * 32768, bl1, B, st, N);
    finalize_kernel<<<1, 128, 0, stream>>>(st, inv_n);
    bnrelu_kernel<<<2048, 256, 0, stream>>>(B, st, g1, be1, N * 32);

    // ----- MLP head -----
    mfma_lin_kernel<0, 1, 0><<<linGrid, 256, 0, stream>>>(
        B, nullptr, wPk + 4 * 32768, nullptr, b1, A, nullptr, N);
    mfma_lin_kernel<0, 1, 0><<<linGrid, 256, 0, stream>>>(
        A, nullptr, wPk + 5 * 32768, nullptr, b2, B, nullptr, N);
    linout_kernel<<<(N + 255) / 256, 256, 0, stream>>>(B, W3, b3, out, N);
}